// Round 1
// baseline (390.891 us; speedup 1.0000x reference)
//
#include <hip/hip_runtime.h>
#include <hip/hip_bf16.h>

#define L 64
#define D 256
#define H 8

typedef __bf16 bf16_t;
typedef bf16_t bf16x4 __attribute__((ext_vector_type(4)));
typedef bf16_t bf16x8 __attribute__((ext_vector_type(8)));
typedef float f32x4 __attribute__((ext_vector_type(4)));

#define MFMA16(a, b, c) __builtin_amdgcn_mfma_f32_16x16x32_bf16(a, b, c, 0, 0, 0)

// ---------------- prep: weights fp32->bf16, mask -> (sigmoid, log(sigmoid+1e-8)) ----------
__global__ void prep_kernel(const float* __restrict__ Wq, const float* __restrict__ Wk,
                            const float* __restrict__ Wv, const float* __restrict__ Wp_,
                            const float* __restrict__ ml,
                            bf16_t* __restrict__ wqkv, bf16_t* __restrict__ wpb,
                            float2* __restrict__ maskpre) {
    int i = blockIdx.x * 256 + threadIdx.x;
    if (i < 196608) {  // 768*256: rows 0-255 = Wq, 256-511 = Wk, 512-767 = Wv
        float v = (i < 65536) ? Wq[i] : ((i < 131072) ? Wk[i - 65536] : Wv[i - 131072]);
        wqkv[i] = (bf16_t)v;
    } else if (i < 262144) {  // 256*256 Wp
        wpb[i - 196608] = (bf16_t)Wp_[i - 196608];
    } else {  // 8*64*64 mask logits
        int j = i - 262144;
        float x = ml[j];
        float m = 1.0f / (1.0f + __expf(-x));
        maskpre[j] = make_float2(m, __logf(m + 1e-8f));
    }
}

// ---------------- fused attention: one block per batch element ----------------
__global__ __launch_bounds__(256, 1) void attn_fused(
    const float* __restrict__ hs_g, const float* __restrict__ graph_g,
    const bf16_t* __restrict__ wqkv, const bf16_t* __restrict__ wp,
    const float* __restrict__ bq, const float* __restrict__ bk,
    const float* __restrict__ bv, const float* __restrict__ bp,
    const float2* __restrict__ maskpre,
    float* __restrict__ y_out, float* __restrict__ att_out) {
    // LDS: 33792*3 + 36864 + 9216 = 147456 B
    __shared__ __align__(16) bf16_t q_lds[64][264];   // stride 264: breaks bank conflicts
    __shared__ __align__(16) bf16_t k_lds[64][264];
    __shared__ __align__(16) bf16_t vT_lds[256][72];  // v transposed: vT[d][row]
    __shared__ __align__(16) bf16_t hy_lds[64][264];  // hidden (bf16), later y
    __shared__ __align__(16) bf16_t p_lds[64][72];    // per-head att probs (bf16)

    const int b = blockIdx.x;
    const int tid = threadIdx.x;
    const int wid = tid >> 6;
    const int lane = tid & 63;
    const int g = lane >> 4;    // 0..3 (K-slice group)
    const int c = lane & 15;    // 0..15
    const int mrow = 16 * wid;  // this wave's M-tile base row

    // ---- Phase 1: hidden fp32 -> bf16 into LDS (coalesced float4 loads) ----
    {
        const float* src = hs_g + (size_t)b * (L * D);
#pragma unroll
        for (int it = 0; it < 16; ++it) {
            int idx = it * 1024 + tid * 4;  // [0, 16384)
            float4 f = *reinterpret_cast<const float4*>(src + idx);
            int row = idx >> 8, col = idx & 255;
            bf16x4 o = {(bf16_t)f.x, (bf16_t)f.y, (bf16_t)f.z, (bf16_t)f.w};
            *reinterpret_cast<bf16x4*>(&hy_lds[row][col]) = o;
        }
    }
    __syncthreads();

    // ---- Phase 2: QKV = hs @ Wqkv^T + bias.  M=64 N=768 K=256 ----
    {
        bf16x8 afrag[8];
#pragma unroll
        for (int ks = 0; ks < 8; ++ks)
            afrag[ks] = *reinterpret_cast<const bf16x8*>(&hy_lds[mrow + c][ks * 32 + g * 8]);

#pragma unroll 4
        for (int nc = 0; nc < 48; ++nc) {
            f32x4 acc = {0.f, 0.f, 0.f, 0.f};
            const bf16_t* wrow = wqkv + (size_t)(nc * 16 + c) * 256 + g * 8;
#pragma unroll
            for (int ks = 0; ks < 8; ++ks) {
                bf16x8 bfrag = *reinterpret_cast<const bf16x8*>(wrow + ks * 32);
                acc = MFMA16(afrag[ks], bfrag, acc);
            }
            int ncol = nc * 16 + c;  // 0..767 (uniform branch: nc decides)
            if (ncol < 256) {
                float bias = bq[ncol];
#pragma unroll
                for (int r = 0; r < 4; ++r)
                    q_lds[mrow + g * 4 + r][ncol] = (bf16_t)(acc[r] + bias);
            } else if (ncol < 512) {
                float bias = bk[ncol - 256];
#pragma unroll
                for (int r = 0; r < 4; ++r)
                    k_lds[mrow + g * 4 + r][ncol - 256] = (bf16_t)(acc[r] + bias);
            } else {
                float bias = bv[ncol - 512];
#pragma unroll
                for (int r = 0; r < 4; ++r)
                    vT_lds[ncol - 512][mrow + g * 4 + r] = (bf16_t)(acc[r] + bias);
            }
        }
    }
    __syncthreads();

    // ---- Phase 3: per-head attention (all LDS per-wave-private -> no barriers) ----
    const float scale = 0.17677669529663687f;  // 1/sqrt(32)
    const float* graphb = graph_g + (size_t)b * (L * L);
    float* attb = att_out + (size_t)b * (H * L * L);

#pragma unroll 1
    for (int h = 0; h < H; ++h) {
        // QK^T: M=64 N=64 K=32 (one K-step). Wave owns its 16 rows, all 4 N-tiles.
        bf16x8 qa = *reinterpret_cast<const bf16x8*>(&q_lds[mrow + c][h * 32 + g * 8]);
        f32x4 s[4];
#pragma unroll
        for (int nt = 0; nt < 4; ++nt) {
            bf16x8 kb = *reinterpret_cast<const bf16x8*>(&k_lds[nt * 16 + c][h * 32 + g * 8]);
            f32x4 z = {0.f, 0.f, 0.f, 0.f};
            s[nt] = MFMA16(qa, kb, z);
        }
        // scale, learned-sigmoid mask, graph gate
        float vals[4][4];
#pragma unroll
        for (int nt = 0; nt < 4; ++nt) {
#pragma unroll
            for (int r = 0; r < 4; ++r) {
                int row = mrow + g * 4 + r;
                int col = nt * 16 + c;
                float2 mp = maskpre[(h * 64 + row) * 64 + col];
                float sv = s[nt][r] * scale;
                sv = sv * mp.x + mp.y;
                sv *= graphb[row * 64 + col];
                vals[nt][r] = sv;
            }
        }
        // softmax over 64 cols: 4 regs (nt) x 16 lanes per row
        float rinv[4];
#pragma unroll
        for (int r = 0; r < 4; ++r) {
            float m = fmaxf(fmaxf(vals[0][r], vals[1][r]), fmaxf(vals[2][r], vals[3][r]));
            m = fmaxf(m, __shfl_xor(m, 1));
            m = fmaxf(m, __shfl_xor(m, 2));
            m = fmaxf(m, __shfl_xor(m, 4));
            m = fmaxf(m, __shfl_xor(m, 8));
            float sum = 0.f;
#pragma unroll
            for (int nt = 0; nt < 4; ++nt) {
                vals[nt][r] = __expf(vals[nt][r] - m);
                sum += vals[nt][r];
            }
            sum += __shfl_xor(sum, 1);
            sum += __shfl_xor(sum, 2);
            sum += __shfl_xor(sum, 4);
            sum += __shfl_xor(sum, 8);
            rinv[r] = 1.0f / sum;
        }
        // write att (fp32, global) + p (bf16, LDS)
#pragma unroll
        for (int nt = 0; nt < 4; ++nt) {
#pragma unroll
            for (int r = 0; r < 4; ++r) {
                int row = mrow + g * 4 + r;
                int col = nt * 16 + c;
                float p = vals[nt][r] * rinv[r];
                attb[(h * 64 + row) * 64 + col] = p;
                p_lds[row][col] = (bf16_t)p;
            }
        }
        // PV: y_h = p @ v_h.  M=64 N=32 K=64
        f32x4 yacc[2] = {{0.f, 0.f, 0.f, 0.f}, {0.f, 0.f, 0.f, 0.f}};
#pragma unroll
        for (int ks = 0; ks < 2; ++ks) {
            bf16x8 pa = *reinterpret_cast<const bf16x8*>(&p_lds[mrow + c][ks * 32 + g * 8]);
#pragma unroll
            for (int nt = 0; nt < 2; ++nt) {
                bf16x8 vb = *reinterpret_cast<const bf16x8*>(
                    &vT_lds[h * 32 + nt * 16 + c][ks * 32 + g * 8]);
                yacc[nt] = MFMA16(pa, vb, yacc[nt]);
            }
        }
#pragma unroll
        for (int nt = 0; nt < 2; ++nt) {
#pragma unroll
            for (int r = 0; r < 4; ++r)
                hy_lds[mrow + g * 4 + r][h * 32 + nt * 16 + c] = (bf16_t)yacc[nt][r];
        }
    }
    __syncthreads();

    // ---- Phase 4: out = y @ Wp^T + bp.  M=64 N=256 K=256 ----
    {
        bf16x8 yfrag[8];
#pragma unroll
        for (int ks = 0; ks < 8; ++ks)
            yfrag[ks] = *reinterpret_cast<const bf16x8*>(&hy_lds[mrow + c][ks * 32 + g * 8]);
        float* yo = y_out + (size_t)b * (L * D);
#pragma unroll 4
        for (int nc = 0; nc < 16; ++nc) {
            f32x4 acc = {0.f, 0.f, 0.f, 0.f};
            const bf16_t* wrow = wp + (size_t)(nc * 16 + c) * 256 + g * 8;
#pragma unroll
            for (int ks = 0; ks < 8; ++ks) {
                bf16x8 bfrag = *reinterpret_cast<const bf16x8*>(wrow + ks * 32);
                acc = MFMA16(yfrag[ks], bfrag, acc);
            }
            int col = nc * 16 + c;
            float bias = bp[col];
#pragma unroll
            for (int r = 0; r < 4; ++r)
                yo[(mrow + g * 4 + r) * 256 + col] = acc[r] + bias;
        }
    }
}

extern "C" void kernel_launch(void* const* d_in, const int* in_sizes, int n_in,
                              void* d_out, int out_size, void* d_ws, size_t ws_size,
                              hipStream_t stream) {
    const float* hs    = (const float*)d_in[0];
    const float* graph = (const float*)d_in[1];
    const float* Wq    = (const float*)d_in[2];
    const float* bq    = (const float*)d_in[3];
    const float* Wk    = (const float*)d_in[4];
    const float* bk    = (const float*)d_in[5];
    const float* Wv    = (const float*)d_in[6];
    const float* bv    = (const float*)d_in[7];
    const float* Wp    = (const float*)d_in[8];
    const float* bp    = (const float*)d_in[9];
    const float* ml    = (const float*)d_in[10];

    bf16_t* wqkv = (bf16_t*)d_ws;                           // 768*256 bf16 = 393216 B
    bf16_t* wpb  = (bf16_t*)((char*)d_ws + 393216);         // 256*256 bf16 = 131072 B
    float2* mpre = (float2*)((char*)d_ws + 524288);         // 8*64*64 float2 = 262144 B

    prep_kernel<<<1152, 256, 0, stream>>>(Wq, Wk, Wv, Wp, ml, wqkv, wpb, mpre);

    float* y_out   = (float*)d_out;                 // 16777216 floats
    float* att_out = y_out + 16777216;              // 33554432 floats
    attn_fused<<<1024, 256, 0, stream>>>(hs, graph, wqkv, wpb, bq, bk, bv, bp, mpre,
                                         y_out, att_out);

    // output 2: mask_logits passthrough (32768 floats)
    hipMemcpyAsync((float*)d_out + 50331648, ml, 32768 * sizeof(float),
                   hipMemcpyDeviceToDevice, stream);
}

// Round 2
// 212.314 us; speedup vs baseline: 1.8411x; 1.8411x over previous
//
#include <hip/hip_runtime.h>
#include <hip/hip_bf16.h>

#define L 64
#define D 256
#define H 8

typedef __bf16 bf16_t;
typedef bf16_t bf16x4 __attribute__((ext_vector_type(4)));
typedef bf16_t bf16x8 __attribute__((ext_vector_type(8)));
typedef float f32x4 __attribute__((ext_vector_type(4)));

#define MFMA16(a, b, c) __builtin_amdgcn_mfma_f32_16x16x32_bf16(a, b, c, 0, 0, 0)

// Output buffer geometry (floats): y [0,16777216) | att [16777216, 50331648) | ml [50331648, +32768)
// Scratch-in-output layout (bytes):
//   k[b]  -> ybytes + b*65536 + 0      (8 heads * 64 l * 32 hd bf16 = 32768 B)
//   vT[b] -> ybytes + b*65536 + 32768  (8 heads * 32 hd * 64 l bf16 = 32768 B)
//   q[b]  -> attbytes + b*131072 + 98304 (32768 B; sits in att heads 6,7 area)

// ---------------- prep: weights fp32->bf16, mask -> (sigmoid, log(sigmoid+1e-8)) ----------
__global__ void prep_kernel(const float* __restrict__ Wq, const float* __restrict__ Wk,
                            const float* __restrict__ Wv, const float* __restrict__ Wp_,
                            const float* __restrict__ ml,
                            bf16_t* __restrict__ wqkv, bf16_t* __restrict__ wpb,
                            float2* __restrict__ maskpre) {
    int i = blockIdx.x * 256 + threadIdx.x;
    if (i < 196608) {  // 768*256: rows 0-255 = Wq, 256-511 = Wk, 512-767 = Wv
        float v = (i < 65536) ? Wq[i] : ((i < 131072) ? Wk[i - 65536] : Wv[i - 131072]);
        wqkv[i] = (bf16_t)v;
    } else if (i < 262144) {  // 256*256 Wp
        wpb[i - 196608] = (bf16_t)Wp_[i - 196608];
    } else {  // 8*64*64 mask logits
        int j = i - 262144;
        float x = ml[j];
        float m = 1.0f / (1.0f + __expf(-x));
        maskpre[j] = make_float2(m, __logf(m + 1e-8f));
    }
}

// ---------------- K2: QKV GEMM. M=65536 (512 blocks x 128 rows), N=768, K=256 ----------------
__global__ __launch_bounds__(512, 4) void qkv_gemm(
    const float* __restrict__ hs, const bf16_t* __restrict__ wqkv,
    const float* __restrict__ bq, const float* __restrict__ bk, const float* __restrict__ bv,
    char* __restrict__ ybytes, char* __restrict__ attbytes) {
    __shared__ __align__(16) char wpan[65536];  // [128][256] bf16, XOR-swizzled
    const int tid = threadIdx.x;
    const int wid = tid >> 6, lane = tid & 63;
    const int g = lane >> 4, c = lane & 15;
    const int wrow = blockIdx.x * 128 + wid * 16;  // wave's 16 rows

    // A fragments: rows wrow+c of hs, fp32 -> bf16, all K=256 in registers
    bf16x8 afr[8];
    {
        const float* ar = hs + (size_t)(wrow + c) * 256;
#pragma unroll
        for (int ks = 0; ks < 8; ++ks) {
            float4 f0 = *reinterpret_cast<const float4*>(ar + ks * 32 + g * 8);
            float4 f1 = *reinterpret_cast<const float4*>(ar + ks * 32 + g * 8 + 4);
            afr[ks] = bf16x8{(bf16_t)f0.x, (bf16_t)f0.y, (bf16_t)f0.z, (bf16_t)f0.w,
                             (bf16_t)f1.x, (bf16_t)f1.y, (bf16_t)f1.z, (bf16_t)f1.w};
        }
    }

#pragma unroll 1
    for (int p = 0; p < 6; ++p) {
        // stage W panel [p*128 .. p*128+128) x 256, reg-staged with XOR swizzle
        uint4 stg[8];
        const char* wsrc = (const char*)wqkv + p * 65536;
#pragma unroll
        for (int rnd = 0; rnd < 8; ++rnd)
            stg[rnd] = *reinterpret_cast<const uint4*>(wsrc + rnd * 8192 + tid * 16);
        __syncthreads();  // WAR: previous panel's reads done
#pragma unroll
        for (int rnd = 0; rnd < 8; ++rnd) {
            int Lo = rnd * 8192 + tid * 16;
            *reinterpret_cast<uint4*>(wpan + (Lo ^ (((Lo >> 9) & 7) << 4))) = stg[rnd];
        }
        __syncthreads();  // RAW: panel visible

#pragma unroll 2
        for (int nc = 0; nc < 8; ++nc) {
            const int brow = nc * 16 + c;
            const int bbase = brow * 512;
            const int swz = (brow & 7) << 4;
            f32x4 acc = {0.f, 0.f, 0.f, 0.f};
#pragma unroll
            for (int ks = 0; ks < 8; ++ks) {
                bf16x8 bfr = *reinterpret_cast<const bf16x8*>(
                    wpan + ((bbase + ks * 64 + g * 16) ^ swz));
                acc = MFMA16(afr[ks], bfr, acc);
            }
            const int ncol = p * 128 + nc * 16 + c;
            if (p < 2) {  // q -> att region
                float bias = bq[ncol];
                int h = ncol >> 5, hd = ncol & 31;
#pragma unroll
                for (int r = 0; r < 4; ++r) {
                    int row = wrow + g * 4 + r;
                    int b = row >> 6, l = row & 63;
                    *reinterpret_cast<bf16_t*>(attbytes + (size_t)b * 131072 + 98304 +
                                               ((h * 64 + l) * 32 + hd) * 2) =
                        (bf16_t)(acc[r] + bias);
                }
            } else if (p < 4) {  // k -> y region
                int cc = ncol - 256;
                float bias = bk[cc];
                int h = cc >> 5, hd = cc & 31;
#pragma unroll
                for (int r = 0; r < 4; ++r) {
                    int row = wrow + g * 4 + r;
                    int b = row >> 6, l = row & 63;
                    *reinterpret_cast<bf16_t*>(ybytes + (size_t)b * 65536 +
                                               ((h * 64 + l) * 32 + hd) * 2) =
                        (bf16_t)(acc[r] + bias);
                }
            } else {  // v -> y region, transposed [hd][l] -> bf16x4 vector store
                int cc = ncol - 512;
                float bias = bv[cc];
                int h = cc >> 5, hd = cc & 31;
                int row0 = wrow + g * 4;
                int b = row0 >> 6, l0 = row0 & 63;
                bf16x4 vv = {(bf16_t)(acc[0] + bias), (bf16_t)(acc[1] + bias),
                             (bf16_t)(acc[2] + bias), (bf16_t)(acc[3] + bias)};
                *reinterpret_cast<bf16x4*>(ybytes + (size_t)b * 65536 + 32768 +
                                           ((h * 32 + hd) * 64 + l0) * 2) = vv;
            }
        }
    }
}

// ---------------- K3: attention + out-proj, one block per batch ----------------
__global__ __launch_bounds__(256, 2) void attn_out(
    const float* __restrict__ graph_g, const float2* __restrict__ maskpre,
    const bf16_t* __restrict__ wp, const float* __restrict__ bp,
    float* __restrict__ y_out, float* __restrict__ att_out) {
    __shared__ __align__(16) bf16_t y_lds[64][264];    // 33792 B
    __shared__ __align__(16) bf16_t p_lds[4][64][72];  // 36864 B  (total 70656 -> 2 blocks/CU)

    const int b = blockIdx.x;
    const int tid = threadIdx.x, wid = tid >> 6, lane = tid & 63;
    const int g = lane >> 4, c = lane & 15;
    const int h0 = wid * 2;

    const char* ybytes = (const char*)y_out;
    const char* attbytes = (const char*)att_out;
    const bf16_t* qb = (const bf16_t*)(attbytes + (size_t)b * 131072 + 98304);  // [8][64][32]
    const bf16_t* kb = (const bf16_t*)(ybytes + (size_t)b * 65536);             // [8][64][32]
    const bf16_t* vtb = kb + 16384;                                             // [8][32][64]
    const float* graphb = graph_g + (size_t)b * 4096;
    float* attb = att_out + (size_t)b * 32768;

    // preload q fragments for both of this wave's heads (q area gets clobbered by att stores)
    bf16x8 qfr[2][4];
#pragma unroll
    for (int hh = 0; hh < 2; ++hh)
#pragma unroll
        for (int mt = 0; mt < 4; ++mt)
            qfr[hh][mt] = *reinterpret_cast<const bf16x8*>(
                qb + (h0 + hh) * 2048 + (mt * 16 + c) * 32 + g * 8);
    __syncthreads();  // all q reads complete before any att store

    const float scale = 0.17677669529663687f;  // 1/sqrt(32)

#pragma unroll 1
    for (int hh = 0; hh < 2; ++hh) {
        const int h = h0 + hh;
        bf16x8 kfr[4];
#pragma unroll
        for (int nt = 0; nt < 4; ++nt)
            kfr[nt] = *reinterpret_cast<const bf16x8*>(
                kb + h * 2048 + (nt * 16 + c) * 32 + g * 8);

#pragma unroll 1
        for (int mt = 0; mt < 4; ++mt) {
            f32x4 S[4];
#pragma unroll
            for (int nt = 0; nt < 4; ++nt) {
                f32x4 z = {0.f, 0.f, 0.f, 0.f};
                S[nt] = MFMA16(qfr[hh][mt], kfr[nt], z);
            }
            float vals[4][4];
#pragma unroll
            for (int nt = 0; nt < 4; ++nt) {
#pragma unroll
                for (int r = 0; r < 4; ++r) {
                    int row = mt * 16 + g * 4 + r, col = nt * 16 + c;
                    float2 mp = maskpre[(h * 64 + row) * 64 + col];
                    float sv = S[nt][r] * scale;
                    sv = sv * mp.x + mp.y;
                    sv *= graphb[row * 64 + col];
                    vals[nt][r] = sv;
                }
            }
#pragma unroll
            for (int r = 0; r < 4; ++r) {
                float m = fmaxf(fmaxf(vals[0][r], vals[1][r]), fmaxf(vals[2][r], vals[3][r]));
                m = fmaxf(m, __shfl_xor(m, 1));
                m = fmaxf(m, __shfl_xor(m, 2));
                m = fmaxf(m, __shfl_xor(m, 4));
                m = fmaxf(m, __shfl_xor(m, 8));
                float s = 0.f;
#pragma unroll
                for (int nt = 0; nt < 4; ++nt) {
                    vals[nt][r] = __expf(vals[nt][r] - m);
                    s += vals[nt][r];
                }
                s += __shfl_xor(s, 1);
                s += __shfl_xor(s, 2);
                s += __shfl_xor(s, 4);
                s += __shfl_xor(s, 8);
                float rinv = 1.0f / s;
                int row = mt * 16 + g * 4 + r;
#pragma unroll
                for (int nt = 0; nt < 4; ++nt) {
                    float pv = vals[nt][r] * rinv;
                    int col = nt * 16 + c;
                    attb[(h * 64 + row) * 64 + col] = pv;
                    p_lds[wid][row][col] = (bf16_t)pv;
                }
            }
        }
        __syncthreads();  // p_lds visible (incl. cross-lane transpose)

        // PV: y_h = p @ v_h  (M=64, N=32, K=64)
        bf16x8 vfr[2][2];
#pragma unroll
        for (int nt2 = 0; nt2 < 2; ++nt2)
#pragma unroll
            for (int ks = 0; ks < 2; ++ks)
                vfr[nt2][ks] = *reinterpret_cast<const bf16x8*>(
                    vtb + h * 2048 + (nt2 * 16 + c) * 64 + ks * 32 + g * 8);
#pragma unroll
        for (int mt = 0; mt < 4; ++mt) {
            f32x4 acc0 = {0.f, 0.f, 0.f, 0.f}, acc1 = {0.f, 0.f, 0.f, 0.f};
#pragma unroll
            for (int ks = 0; ks < 2; ++ks) {
                bf16x8 pa = *reinterpret_cast<const bf16x8*>(
                    &p_lds[wid][mt * 16 + c][ks * 32 + g * 8]);
                acc0 = MFMA16(pa, vfr[0][ks], acc0);
                acc1 = MFMA16(pa, vfr[1][ks], acc1);
            }
#pragma unroll
            for (int r = 0; r < 4; ++r) {
                y_lds[mt * 16 + g * 4 + r][h * 32 + c] = (bf16_t)acc0[r];
                y_lds[mt * 16 + g * 4 + r][h * 32 + 16 + c] = (bf16_t)acc1[r];
            }
        }
        __syncthreads();  // y_lds visible; WAR guard for next head's p writes
    }

    // out-proj: out = y @ Wp^T + bp.  Wave owns 64 N-cols; B-frags reused across M-tiles.
#pragma unroll 1
    for (int nc4 = 0; nc4 < 4; ++nc4) {
        const int ncol = wid * 64 + nc4 * 16 + c;
        bf16x8 bfr[8];
#pragma unroll
        for (int ks = 0; ks < 8; ++ks)
            bfr[ks] = *reinterpret_cast<const bf16x8*>(wp + (size_t)ncol * 256 + ks * 32 + g * 8);
        const float bias = bp[ncol];
#pragma unroll
        for (int mt = 0; mt < 4; ++mt) {
            f32x4 acc = {0.f, 0.f, 0.f, 0.f};
#pragma unroll
            for (int ks = 0; ks < 8; ++ks) {
                bf16x8 afr2 = *reinterpret_cast<const bf16x8*>(
                    &y_lds[mt * 16 + c][ks * 32 + g * 8]);
                acc = MFMA16(afr2, bfr[ks], acc);
            }
#pragma unroll
            for (int r = 0; r < 4; ++r)
                y_out[(size_t)b * 16384 + (mt * 16 + g * 4 + r) * 256 + ncol] = acc[r] + bias;
        }
    }
}

extern "C" void kernel_launch(void* const* d_in, const int* in_sizes, int n_in,
                              void* d_out, int out_size, void* d_ws, size_t ws_size,
                              hipStream_t stream) {
    const float* hs    = (const float*)d_in[0];
    const float* graph = (const float*)d_in[1];
    const float* Wq    = (const float*)d_in[2];
    const float* bq    = (const float*)d_in[3];
    const float* Wk    = (const float*)d_in[4];
    const float* bk    = (const float*)d_in[5];
    const float* Wv    = (const float*)d_in[6];
    const float* bv    = (const float*)d_in[7];
    const float* Wp    = (const float*)d_in[8];
    const float* bp    = (const float*)d_in[9];
    const float* ml    = (const float*)d_in[10];

    bf16_t* wqkv = (bf16_t*)d_ws;                    // 768*256 bf16 = 393216 B
    bf16_t* wpb  = (bf16_t*)((char*)d_ws + 393216);  // 256*256 bf16 = 131072 B
    float2* mpre = (float2*)((char*)d_ws + 524288);  // 8*64*64 float2 = 262144 B

    float* y_out   = (float*)d_out;       // 16777216 floats
    float* att_out = y_out + 16777216;    // 33554432 floats
    char*  ybytes  = (char*)d_out;
    char*  attbytes = (char*)d_out + 67108864;

    prep_kernel<<<1152, 256, 0, stream>>>(Wq, Wk, Wv, Wp, ml, wqkv, wpb, mpre);
    qkv_gemm<<<512, 512, 0, stream>>>(hs, wqkv, bq, bk, bv, ybytes, attbytes);
    attn_out<<<1024, 256, 0, stream>>>(graph, mpre, wpb, bp, y_out, att_out);

    // output 2: mask_logits passthrough (32768 floats)
    hipMemcpyAsync((float*)d_out + 50331648, ml, 32768 * sizeof(float),
                   hipMemcpyDeviceToDevice, stream);
}